// Round 1
// baseline (807.204 us; speedup 1.0000x reference)
//
#include <hip/hip_runtime.h>

#define TT   110          // max_seq_len
#define BBD  256          // num dialogues
#define NND  28160        // TT*BBD
#define WIN  10

__device__ __forceinline__ int imax(int a, int b){ return a > b ? a : b; }
__device__ __forceinline__ int imin(int a, int b){ return a < b ? a : b; }

#define FMA4(ACC, S, B) { (ACC).x += (S)*(B).x; (ACC).y += (S)*(B).y; \
                          (ACC).z += (S)*(B).z; (ACC).w += (S)*(B).w; }

// ---------------------------------------------------------------------------
// K0: Wrels[r][f][h] = sum_nb comp[r][nb]*basis[nb][f][h]  (r<8); Wrels[8]=root
// ---------------------------------------------------------------------------
__global__ __launch_bounds__(256) void wrels_k(
    const float* __restrict__ basis, const float* __restrict__ comp,
    const float* __restrict__ root, float* __restrict__ wrels)
{
  int idx = blockIdx.x * 256 + threadIdx.x;        // 9*12800 = 115200
  if (idx >= 115200) return;
  int r = idx / 12800, fh = idx % 12800;
  float v;
  if (r < 8) {
    v = 0.f;
    #pragma unroll
    for (int nb = 0; nb < 30; ++nb) v += comp[r*30 + nb] * basis[nb*12800 + fh];
  } else {
    v = root[fh];
  }
  wrels[idx] = v;
}

// ---------------------------------------------------------------------------
// Generic register-tiled f32 GEMM: C[M x Ncols] = A[M x K] * B[K x Ncols] (+bias)
// BM=256, BN=64, BK=16; 256 threads, 16x4 micro-tile per thread.
// MODE 0: fusion   A=concat(textf,acouf,visuf) gathered (n=b*T+t), B=Wf[300x200]
// MODE 1: xr       A=x[N x 200],             B=wrels[(c>>6)][k][c&63]
// MODE 2: Xq       A=[x | h2],               B=Wma[264x264]
// MODE 3: h2       A=[agg | h1],             B=[Wrel ; Wroot2]
// MODE 4: hidden   A=att[N x 264],           B=Wl[264x64], RELU
// ---------------------------------------------------------------------------
template<int MODE, bool RELU>
__global__ __launch_bounds__(256) void gemm_k(
    const float* __restrict__ p0, const float* __restrict__ p1,
    const float* __restrict__ p2, const float* __restrict__ p3,
    const float* __restrict__ bias, float* __restrict__ C,
    int Ncols, int K)
{
  __shared__ float As[16][264];
  __shared__ float Bs[16][72];
  const int tid = threadIdx.x;
  const int m0 = blockIdx.y * 256;
  const int n0 = blockIdx.x * 64;
  const int ka = tid & 15, ma = tid >> 4;     // A-load: k fast, 16 rows/thread
  const int kb = tid >> 6, cb = tid & 63;     // B-load: col fast
  const int ty = tid >> 4, tx = tid & 15;     // compute: rows ty*16.., cols tx*4..

  int ab1[16], ab2[16];
  #pragma unroll
  for (int p = 0; p < 16; ++p) {
    int n = m0 + ma + (p << 4);
    if constexpr (MODE == 0) {
      int t = n % TT, b = n / TT;
      ab1[p] = (t * BBD + b) * 100; ab2[p] = 0;
    } else if constexpr (MODE == 1) { ab1[p] = n * 200; ab2[p] = 0; }
    else if constexpr (MODE == 2)   { ab1[p] = n * 200; ab2[p] = n * 64; }
    else if constexpr (MODE == 3)   { ab1[p] = n * 64;  ab2[p] = n * 64; }
    else                            { ab1[p] = n * 264; ab2[p] = 0; }
  }
  const int gc = n0 + cb;
  int bcol = 0;
  if constexpr (MODE == 1) bcol = (n0 >> 6) * 12800 + cb;

  float4 acc[16];
  #pragma unroll
  for (int i = 0; i < 16; ++i) acc[i] = make_float4(0.f,0.f,0.f,0.f);

  const int nk = (K + 15) >> 4;
  for (int kt = 0; kt < nk; ++kt) {
    const int k0 = kt << 4;
    { // A tile
      const int gk = k0 + ka;
      const bool kok = gk < K;
      #pragma unroll
      for (int p = 0; p < 16; ++p) {
        float v = 0.f;
        if (kok) {
          if constexpr (MODE == 0) {
            v = (gk < 100) ? p0[ab1[p] + gk]
              : (gk < 200) ? p1[ab1[p] + gk - 100]
                           : p2[ab1[p] + gk - 200];
          } else if constexpr (MODE == 1) v = p0[ab1[p] + gk];
          else if constexpr (MODE == 2) v = (gk < 200) ? p0[ab1[p]+gk] : p1[ab2[p]+gk-200];
          else if constexpr (MODE == 3) v = (gk < 64)  ? p0[ab1[p]+gk] : p1[ab2[p]+gk-64];
          else v = p0[ab1[p] + gk];
        }
        As[ka][ma + (p << 4)] = v;
      }
    }
    { // B tile
      #pragma unroll
      for (int p = 0; p < 4; ++p) {
        const int kk = kb + (p << 2);
        const int gk = k0 + kk;
        float v = 0.f;
        if (gk < K && gc < Ncols) {
          if constexpr (MODE == 0) v = p3[gk*200 + gc];
          else if constexpr (MODE == 1) v = p3[bcol + gk*64];
          else if constexpr (MODE == 2) v = p3[gk*264 + gc];
          else if constexpr (MODE == 3) v = (gk < 64) ? p3[gk*64+gc] : p2[(gk-64)*64+gc];
          else v = p3[gk*64 + gc];
        }
        Bs[kk][cb] = v;
      }
    }
    __syncthreads();
    #pragma unroll
    for (int kk = 0; kk < 16; ++kk) {
      const float4 b4 = *(const float4*)&Bs[kk][tx << 2];
      const float* ar = &As[kk][ty << 4];
      #pragma unroll
      for (int ia = 0; ia < 4; ++ia) {
        const float4 a4 = *(const float4*)&ar[ia << 2];
        FMA4(acc[ia*4+0], a4.x, b4);
        FMA4(acc[ia*4+1], a4.y, b4);
        FMA4(acc[ia*4+2], a4.z, b4);
        FMA4(acc[ia*4+3], a4.w, b4);
      }
    }
    __syncthreads();
  }
  const int gc0 = n0 + (tx << 2);
  if (gc0 < Ncols) {
    float4 bv = make_float4(0.f,0.f,0.f,0.f);
    if (bias) bv = *(const float4*)&bias[gc0];
    #pragma unroll
    for (int i = 0; i < 16; ++i) {
      const int gm = m0 + (ty << 4) + i;
      float4 o;
      o.x = acc[i].x + bv.x; o.y = acc[i].y + bv.y;
      o.z = acc[i].z + bv.z; o.w = acc[i].w + bv.w;
      if (RELU) {
        o.x = fmaxf(o.x, 0.f); o.y = fmaxf(o.y, 0.f);
        o.z = fmaxf(o.z, 0.f); o.w = fmaxf(o.w, 0.f);
      }
      *(float4*)&C[(size_t)gm * Ncols + gc0] = o;
    }
  }
}

// ---------------------------------------------------------------------------
// K3: RGCN windowed per-relation mean aggregation. One wave per dst node.
// Only 4 relations are live per dst (its speaker fixes s1): index by (s0,dir).
// h1[n] = sum_r mean_r + xr[n][root slot] + b_rgcn
// ---------------------------------------------------------------------------
__global__ __launch_bounds__(256) void rgcn_agg_k(
    const float* __restrict__ xr, const int* __restrict__ spk,
    const float* __restrict__ brg, float* __restrict__ h1)
{
  const int n = (blockIdx.x << 2) + (threadIdx.x >> 6);
  const int lane = threadIdx.x & 63;
  const int t = n % TT, b = n / TT;
  const int si2 = spk[t * BBD + b] << 1;
  const int jlo = imax(t - WIN, 0), jhi = imin(t + WIN, TT - 1);
  float a00=0.f, a01=0.f, a10=0.f, a11=0.f;
  int c00=0, c01=0, c10=0, c11=0;
  const size_t rb = (size_t)b * TT;
  for (int j = jlo; j <= jhi; ++j) {
    const int s0 = spk[j * BBD + b];
    const int dir = (j >= t) ? 1 : 0;
    const int r = (s0 << 2) + si2 + dir;
    const float v = xr[(rb + j) * 576 + (r << 6) + lane];
    if (s0) { if (dir) { a11 += v; ++c11; } else { a10 += v; ++c10; } }
    else    { if (dir) { a01 += v; ++c01; } else { a00 += v; ++c00; } }
  }
  float res = a00 / (float)imax(c00,1) + a01 / (float)imax(c01,1)
            + a10 / (float)imax(c10,1) + a11 / (float)imax(c11,1);
  res += xr[(size_t)n * 576 + 512 + lane] + brg[lane];
  h1[(size_t)n * 64 + lane] = res;
}

// K4a: agg[n] = sum over window of h1[j]
__global__ __launch_bounds__(256) void gsum_k(
    const float* __restrict__ h1, float* __restrict__ agg)
{
  const int n = (blockIdx.x << 2) + (threadIdx.x >> 6);
  const int lane = threadIdx.x & 63;
  const int t = n % TT, b = n / TT;
  const int jlo = imax(t - WIN, 0), jhi = imin(t + WIN, TT - 1);
  float a = 0.f;
  const size_t rb = (size_t)b * TT;
  for (int j = jlo; j <= jhi; ++j) a += h1[(rb + j) * 64 + lane];
  agg[(size_t)n * 64 + lane] = a;
}

// ---------------------------------------------------------------------------
// K6: matching attention, one block (512 thr) per dialogue.
// M (110 x 264, padded 268) in LDS; per wave 4 queries register-blocked.
// ---------------------------------------------------------------------------
__global__ __launch_bounds__(512) void attn_k(
    const float* __restrict__ x, const float* __restrict__ h2,
    const float* __restrict__ Xq, float* __restrict__ att)
{
  __shared__ float Msh[TT][268];
  __shared__ float Qsh[8][4][268];
  const int b = blockIdx.x;
  const int tid = threadIdx.x;
  for (int idx = tid; idx < TT * 66; idx += 512) {
    const int row = idx / 66, c4 = idx % 66;
    const size_t node = (size_t)b * TT + row;
    float4 v;
    if (c4 < 50) v = *(const float4*)&x[node * 200 + (c4 << 2)];
    else         v = *(const float4*)&h2[node * 64 + ((c4 - 50) << 2)];
    *(float4*)&Msh[row][c4 << 2] = v;
  }
  __syncthreads();
  const int w = tid >> 6, lane = tid & 63;
  for (int p = 0; p < 4; ++p) {
    const int t0 = (p << 5) + (w << 2);
    if (t0 >= TT) break;                      // uniform per wave; no barriers below
    #pragma unroll
    for (int qi = 0; qi < 4; ++qi) {
      const int t = t0 + qi;
      if (t < TT) {
        const float* src = &Xq[((size_t)b * TT + t) * 264];
        *(float4*)&Qsh[w][qi][lane << 2] = *(const float4*)&src[lane << 2];
        if (lane < 2)
          *(float4*)&Qsh[w][qi][(64 + lane) << 2] = *(const float4*)&src[(64 + lane) << 2];
      }
    }
    float s0[4] = {0,0,0,0}, s1[4] = {0,0,0,0};
    for (int d4 = 0; d4 < 66; ++d4) {
      const float4 m0 = *(const float4*)&Msh[lane][d4 << 2];
      float4 m1 = make_float4(0.f,0.f,0.f,0.f);
      if (lane < 46) m1 = *(const float4*)&Msh[64 + lane][d4 << 2];
      #pragma unroll
      for (int qi = 0; qi < 4; ++qi) {
        const float4 q = *(const float4*)&Qsh[w][qi][d4 << 2];
        s0[qi] += q.x*m0.x + q.y*m0.y + q.z*m0.z + q.w*m0.w;
        s1[qi] += q.x*m1.x + q.y*m1.y + q.z*m1.z + q.w*m1.w;
      }
    }
    float al0[4], al1[4];
    #pragma unroll
    for (int qi = 0; qi < 4; ++qi) {
      const float v0 = tanhf(s0[qi]);
      const float v1 = (lane < 46) ? tanhf(s1[qi]) : -3.0e38f;
      float mx = fmaxf(v0, v1);
      #pragma unroll
      for (int o = 32; o >= 1; o >>= 1) mx = fmaxf(mx, __shfl_xor(mx, o));
      const float e0 = __expf(v0 - mx);
      const float e1 = (lane < 46) ? __expf(v1 - mx) : 0.f;
      float sm = e0 + e1;
      #pragma unroll
      for (int o = 32; o >= 1; o >>= 1) sm += __shfl_xor(sm, o);
      const float inv = 1.f / sm;
      al0[qi] = e0 * inv; al1[qi] = e1 * inv;
    }
    float4 accA[4], accB[4];
    #pragma unroll
    for (int qi = 0; qi < 4; ++qi) {
      accA[qi] = make_float4(0.f,0.f,0.f,0.f);
      accB[qi] = make_float4(0.f,0.f,0.f,0.f);
    }
    for (int s = 0; s < TT; ++s) {
      const float4 mv = *(const float4*)&Msh[s][lane << 2];
      float4 mv2 = make_float4(0.f,0.f,0.f,0.f);
      if (lane < 2) mv2 = *(const float4*)&Msh[s][(64 + lane) << 2];
      #pragma unroll
      for (int qi = 0; qi < 4; ++qi) {
        const float av = __shfl((s < 64) ? al0[qi] : al1[qi], s & 63);
        FMA4(accA[qi], av, mv);
        FMA4(accB[qi], av, mv2);
      }
    }
    #pragma unroll
    for (int qi = 0; qi < 4; ++qi) {
      const int t = t0 + qi;
      if (t < TT) {
        float* dst = &att[((size_t)b * TT + t) * 264];
        *(float4*)&dst[lane << 2] = accA[qi];
        if (lane < 2) *(float4*)&dst[256 + (lane << 2)] = accB[qi];
      }
    }
  }
}

// ---------------------------------------------------------------------------
// K7b: logits + log_softmax. 8 lanes per node (7 classes), 32 nodes/block.
// ---------------------------------------------------------------------------
__global__ __launch_bounds__(256) void logits_k(
    const float* __restrict__ hid, const float* __restrict__ Ws,
    const float* __restrict__ bs, float* __restrict__ out)
{
  const int tid = threadIdx.x;
  const int n = blockIdx.x * 32 + (tid >> 3);
  const int c = tid & 7;
  float lg = -3.0e38f;
  if (c < 7) {
    lg = bs[c];
    const float* hrow = &hid[(size_t)n * 64];
    #pragma unroll
    for (int k = 0; k < 64; ++k) lg += hrow[k] * Ws[k*7 + c];
  }
  float mx = lg;
  #pragma unroll
  for (int o = 4; o >= 1; o >>= 1) mx = fmaxf(mx, __shfl_xor(mx, o, 8));
  float e = (c < 7) ? __expf(lg - mx) : 0.f;
  float sm = e;
  #pragma unroll
  for (int o = 4; o >= 1; o >>= 1) sm += __shfl_xor(sm, o, 8);
  if (c < 7) out[(size_t)n * 7 + c] = lg - mx - __logf(sm);
}

// ---------------------------------------------------------------------------
extern "C" void kernel_launch(void* const* d_in, const int* in_sizes, int n_in,
                              void* d_out, int out_size, void* d_ws, size_t ws_size,
                              hipStream_t stream)
{
  const float* textf  = (const float*)d_in[0];
  const float* acouf  = (const float*)d_in[1];
  const float* visuf  = (const float*)d_in[2];
  const int*   spk    = (const int*)  d_in[3];
  const float* Wf     = (const float*)d_in[4];
  const float* bfv    = (const float*)d_in[5];
  const float* basis  = (const float*)d_in[6];
  const float* comp   = (const float*)d_in[7];
  const float* root   = (const float*)d_in[8];
  const float* brg    = (const float*)d_in[9];
  const float* Wrel   = (const float*)d_in[10];
  const float* brel   = (const float*)d_in[11];
  const float* Wroot2 = (const float*)d_in[12];
  const float* Wma    = (const float*)d_in[13];
  const float* bma    = (const float*)d_in[14];
  const float* Wl     = (const float*)d_in[15];
  const float* bl     = (const float*)d_in[16];
  const float* Wsm    = (const float*)d_in[17];
  const float* bsm    = (const float*)d_in[18];

  float* ws    = (float*)d_ws;
  float* wrels = ws;                         // 115200
  float* xb    = ws + 115200;                // N*200 = 5632000
  float* xr    = xb + 5632000;               // N*576 = 16220160
  float* h1    = xr + 16220160;              // N*64  = 1802240
  float* h2    = h1 + 1802240;               // N*64  = 1802240
  float* agg   = xr;                         // alias (xr dead after rgcn_agg)
  float* attb  = xr;                         // alias (agg dead after gemm<3>)
  float* Xq    = xr + 7434240;               // alias upper half of xr region
  float* hid   = h1;                         // alias (h1 dead after gemm<3>)
  float* outp  = (float*)d_out;

  wrels_k<<<450, 256, 0, stream>>>(basis, comp, root, wrels);
  gemm_k<0,false><<<dim3(4,110), 256, 0, stream>>>(textf, acouf, visuf, Wf, bfv, xb, 200, 300);
  gemm_k<1,false><<<dim3(9,110), 256, 0, stream>>>(xb, nullptr, nullptr, wrels, nullptr, xr, 576, 200);
  rgcn_agg_k<<<7040, 256, 0, stream>>>(xr, spk, brg, h1);
  gsum_k<<<7040, 256, 0, stream>>>(h1, agg);
  gemm_k<3,false><<<dim3(1,110), 256, 0, stream>>>(agg, h1, Wroot2, Wrel, brel, h2, 64, 128);
  gemm_k<2,false><<<dim3(5,110), 256, 0, stream>>>(xb, h2, nullptr, Wma, bma, Xq, 264, 264);
  attn_k<<<256, 512, 0, stream>>>(xb, h2, Xq, attb);
  gemm_k<4,true><<<dim3(1,110), 256, 0, stream>>>(attb, nullptr, nullptr, Wl, bl, hid, 64, 264);
  logits_k<<<880, 256, 0, stream>>>(hid, Wsm, bsm, outp);
}

// Round 2
// 616.560 us; speedup vs baseline: 1.3092x; 1.3092x over previous
//
#include <hip/hip_runtime.h>

#define TT   110          // max_seq_len
#define BBD  256          // num dialogues
#define NND  28160        // TT*BBD
#define WIN  10

typedef __bf16 bf16x8 __attribute__((ext_vector_type(8)));
typedef float  f32x4  __attribute__((ext_vector_type(4)));

__device__ __forceinline__ int imax(int a, int b){ return a > b ? a : b; }
__device__ __forceinline__ int imin(int a, int b){ return a < b ? a : b; }

#define FMA4(ACC, S, B) { (ACC).x += (S)*(B).x; (ACC).y += (S)*(B).y; \
                          (ACC).z += (S)*(B).z; (ACC).w += (S)*(B).w; }

// ---------------------------------------------------------------------------
// K0: Wrels[r][f][h] = sum_nb comp[r][nb]*basis[nb][f][h]  (r<8); Wrels[8]=root
// ---------------------------------------------------------------------------
__global__ __launch_bounds__(256) void wrels_k(
    const float* __restrict__ basis, const float* __restrict__ comp,
    const float* __restrict__ root, float* __restrict__ wrels)
{
  int idx = blockIdx.x * 256 + threadIdx.x;        // 9*12800 = 115200
  if (idx >= 115200) return;
  int r = idx / 12800, fh = idx % 12800;
  float v;
  if (r < 8) {
    v = 0.f;
    #pragma unroll
    for (int nb = 0; nb < 30; ++nb) v += comp[r*30 + nb] * basis[nb*12800 + fh];
  } else {
    v = root[fh];
  }
  wrels[idx] = v;
}

// ---------------------------------------------------------------------------
// MFMA bf16 GEMM: C[M x Ncols] = A[M x K] * B[K x Ncols] (+bias, opt ReLU)
// BM=128, BN=64, BK=32. 256 thr = 4 waves (2x2), each wave 64x32 = 4x2 frags
// of v_mfma_f32_16x16x32_bf16. A,B staged f32->bf16 into LDS; stride 40 bf16
// (80 B = multiple of 16 B, 2-way bank aliasing = free).
// MODE 0: fusion   A=concat(textf,acouf,visuf) gathered (n=b*T+t), B=Wf[300x200]
// MODE 1: xr       A=x[N x 200],  B=wrels[(c>>6)][k][c&63]
// MODE 2: Xq       A=[x | h2],    B=Wma[264x264]
// MODE 3: h2       A=[agg | h1],  B=[Wrel ; Wroot2]
// MODE 4: hidden   A=att[N x 264],B=Wl[264x64], RELU
// ---------------------------------------------------------------------------
template<int MODE, bool RELU>
__global__ __launch_bounds__(256) void mgemm_k(
    const float* __restrict__ p0, const float* __restrict__ p1,
    const float* __restrict__ p2, const float* __restrict__ p3,
    const float* __restrict__ bias, float* __restrict__ C,
    int Ncols, int K)
{
  __shared__ __align__(16) __bf16 Ash[128][40];
  __shared__ __align__(16) __bf16 Bsh[64][40];
  const int tid = threadIdx.x;
  const int m0 = blockIdx.y * 128;
  const int n0 = blockIdx.x * 64;

  const int ar = tid >> 2;            // A stage: rows ar, ar+64
  const int ak = (tid & 3) << 3;      //          k-chunk of 8
  const int bc = tid & 63;            // B stage: col
  const int bk = (tid >> 6) << 3;     //          k-chunk of 8

  const int wid = tid >> 6, lane = tid & 63;
  const int wm = wid >> 1, wn = wid & 1;
  const int fr = lane & 15;           // fragment non-K index
  const int fk = (lane >> 4) << 3;    // fragment K base

  int base1[2], base2[2];
  #pragma unroll
  for (int p = 0; p < 2; ++p) {
    const int n = m0 + ar + (p << 6);
    if constexpr (MODE == 0) { const int t = n % TT, b = n / TT; base1[p] = (t*BBD+b)*100; base2[p] = 0; }
    else if constexpr (MODE == 1) { base1[p] = n*200; base2[p] = 0; }
    else if constexpr (MODE == 2) { base1[p] = n*200; base2[p] = n*64; }
    else if constexpr (MODE == 3) { base1[p] = n*64;  base2[p] = n*64; }
    else                          { base1[p] = n*264; base2[p] = 0; }
  }
  int bbase = 0;
  if constexpr (MODE == 1) bbase = (n0 >> 6) * 12800 + bc;
  const int gc = n0 + bc;

  f32x4 acc[4][2];
  #pragma unroll
  for (int f = 0; f < 4; ++f)
    #pragma unroll
    for (int g = 0; g < 2; ++g) acc[f][g] = (f32x4){0.f, 0.f, 0.f, 0.f};

  const int nk = (K + 31) >> 5;
  for (int kt = 0; kt < nk; ++kt) {
    const int k0 = kt << 5;
    // ---- stage A (f32 -> bf16) ----
    #pragma unroll
    for (int p = 0; p < 2; ++p) {
      bf16x8 v;
      #pragma unroll
      for (int e = 0; e < 8; ++e) {
        const int gk = k0 + ak + e;
        float x = 0.f;
        if (gk < K) {
          if constexpr (MODE == 0)
            x = (gk < 100) ? p0[base1[p]+gk] : (gk < 200) ? p1[base1[p]+gk-100] : p2[base1[p]+gk-200];
          else if constexpr (MODE == 2)
            x = (gk < 200) ? p0[base1[p]+gk] : p1[base2[p]+gk-200];
          else if constexpr (MODE == 3)
            x = (gk < 64) ? p0[base1[p]+gk] : p1[base2[p]+gk-64];
          else
            x = p0[base1[p]+gk];
        }
        v[e] = (__bf16)x;
      }
      *(bf16x8*)&Ash[ar + (p << 6)][ak] = v;
    }
    // ---- stage B transposed (f32 -> bf16): Bsh[col][k] ----
    {
      bf16x8 v;
      #pragma unroll
      for (int e = 0; e < 8; ++e) {
        const int gk = k0 + bk + e;
        float x = 0.f;
        if (gk < K && gc < Ncols) {
          if constexpr (MODE == 0)      x = p3[gk*200 + gc];
          else if constexpr (MODE == 1) x = p3[bbase + gk*64];
          else if constexpr (MODE == 2) x = p3[gk*264 + gc];
          else if constexpr (MODE == 3) x = (gk < 64) ? p3[gk*64 + gc] : p2[(gk-64)*64 + gc];
          else                          x = p3[gk*64 + gc];
        }
        v[e] = (__bf16)x;
      }
      *(bf16x8*)&Bsh[bc][bk] = v;
    }
    __syncthreads();
    bf16x8 af[4], bfv[2];
    #pragma unroll
    for (int f = 0; f < 4; ++f) af[f] = *(bf16x8*)&Ash[wm*64 + f*16 + fr][fk];
    #pragma unroll
    for (int g = 0; g < 2; ++g) bfv[g] = *(bf16x8*)&Bsh[wn*32 + g*16 + fr][fk];
    #pragma unroll
    for (int f = 0; f < 4; ++f)
      #pragma unroll
      for (int g = 0; g < 2; ++g)
        acc[f][g] = __builtin_amdgcn_mfma_f32_16x16x32_bf16(af[f], bfv[g], acc[f][g], 0, 0, 0);
    __syncthreads();
  }
  // ---- epilogue: D layout col=lane&15, row=(lane>>4)*4+reg ----
  const int row0 = (lane >> 4) << 2;
  #pragma unroll
  for (int g = 0; g < 2; ++g) {
    const int col = n0 + wn*32 + g*16 + fr;
    if (col < Ncols) {
      const float bv = bias ? bias[col] : 0.f;
      #pragma unroll
      for (int f = 0; f < 4; ++f) {
        const int gm0 = m0 + wm*64 + f*16 + row0;
        #pragma unroll
        for (int r = 0; r < 4; ++r) {
          float v = acc[f][g][r] + bv;
          if (RELU) v = fmaxf(v, 0.f);
          C[(size_t)(gm0 + r) * Ncols + col] = v;
        }
      }
    }
  }
}

// ---------------------------------------------------------------------------
// K3: RGCN windowed per-relation mean aggregation. One wave per dst node.
// ---------------------------------------------------------------------------
__global__ __launch_bounds__(256) void rgcn_agg_k(
    const float* __restrict__ xr, const int* __restrict__ spk,
    const float* __restrict__ brg, float* __restrict__ h1)
{
  const int n = (blockIdx.x << 2) + (threadIdx.x >> 6);
  const int lane = threadIdx.x & 63;
  const int t = n % TT, b = n / TT;
  const int si2 = spk[t * BBD + b] << 1;
  const int jlo = imax(t - WIN, 0), jhi = imin(t + WIN, TT - 1);
  float a00=0.f, a01=0.f, a10=0.f, a11=0.f;
  int c00=0, c01=0, c10=0, c11=0;
  const size_t rb = (size_t)b * TT;
  for (int j = jlo; j <= jhi; ++j) {
    const int s0 = spk[j * BBD + b];
    const int dir = (j >= t) ? 1 : 0;
    const int r = (s0 << 2) + si2 + dir;
    const float v = xr[(rb + j) * 576 + (r << 6) + lane];
    if (s0) { if (dir) { a11 += v; ++c11; } else { a10 += v; ++c10; } }
    else    { if (dir) { a01 += v; ++c01; } else { a00 += v; ++c00; } }
  }
  float res = a00 / (float)imax(c00,1) + a01 / (float)imax(c01,1)
            + a10 / (float)imax(c10,1) + a11 / (float)imax(c11,1);
  res += xr[(size_t)n * 576 + 512 + lane] + brg[lane];
  h1[(size_t)n * 64 + lane] = res;
}

// K4a: agg[n] = sum over window of h1[j]
__global__ __launch_bounds__(256) void gsum_k(
    const float* __restrict__ h1, float* __restrict__ agg)
{
  const int n = (blockIdx.x << 2) + (threadIdx.x >> 6);
  const int lane = threadIdx.x & 63;
  const int t = n % TT, b = n / TT;
  const int jlo = imax(t - WIN, 0), jhi = imin(t + WIN, TT - 1);
  float a = 0.f;
  const size_t rb = (size_t)b * TT;
  for (int j = jlo; j <= jhi; ++j) a += h1[(rb + j) * 64 + lane];
  agg[(size_t)n * 64 + lane] = a;
}

// ---------------------------------------------------------------------------
// K6: matching attention, one block (512 thr) per dialogue.
// ---------------------------------------------------------------------------
__global__ __launch_bounds__(512) void attn_k(
    const float* __restrict__ x, const float* __restrict__ h2,
    const float* __restrict__ Xq, float* __restrict__ att)
{
  __shared__ float Msh[TT][268];
  __shared__ float Qsh[8][4][268];
  const int b = blockIdx.x;
  const int tid = threadIdx.x;
  for (int idx = tid; idx < TT * 66; idx += 512) {
    const int row = idx / 66, c4 = idx % 66;
    const size_t node = (size_t)b * TT + row;
    float4 v;
    if (c4 < 50) v = *(const float4*)&x[node * 200 + (c4 << 2)];
    else         v = *(const float4*)&h2[node * 64 + ((c4 - 50) << 2)];
    *(float4*)&Msh[row][c4 << 2] = v;
  }
  __syncthreads();
  const int w = tid >> 6, lane = tid & 63;
  for (int p = 0; p < 4; ++p) {
    const int t0 = (p << 5) + (w << 2);
    if (t0 >= TT) break;                      // uniform per wave
    #pragma unroll
    for (int qi = 0; qi < 4; ++qi) {
      const int t = t0 + qi;
      if (t < TT) {
        const float* src = &Xq[((size_t)b * TT + t) * 264];
        *(float4*)&Qsh[w][qi][lane << 2] = *(const float4*)&src[lane << 2];
        if (lane < 2)
          *(float4*)&Qsh[w][qi][(64 + lane) << 2] = *(const float4*)&src[(64 + lane) << 2];
      }
    }
    float s0[4] = {0,0,0,0}, s1[4] = {0,0,0,0};
    for (int d4 = 0; d4 < 66; ++d4) {
      const float4 m0 = *(const float4*)&Msh[lane][d4 << 2];
      float4 m1 = make_float4(0.f,0.f,0.f,0.f);
      if (lane < 46) m1 = *(const float4*)&Msh[64 + lane][d4 << 2];
      #pragma unroll
      for (int qi = 0; qi < 4; ++qi) {
        const float4 q = *(const float4*)&Qsh[w][qi][d4 << 2];
        s0[qi] += q.x*m0.x + q.y*m0.y + q.z*m0.z + q.w*m0.w;
        s1[qi] += q.x*m1.x + q.y*m1.y + q.z*m1.z + q.w*m1.w;
      }
    }
    float al0[4], al1[4];
    #pragma unroll
    for (int qi = 0; qi < 4; ++qi) {
      const float v0 = tanhf(s0[qi]);
      const float v1 = (lane < 46) ? tanhf(s1[qi]) : -3.0e38f;
      float mx = fmaxf(v0, v1);
      #pragma unroll
      for (int o = 32; o >= 1; o >>= 1) mx = fmaxf(mx, __shfl_xor(mx, o));
      const float e0 = __expf(v0 - mx);
      const float e1 = (lane < 46) ? __expf(v1 - mx) : 0.f;
      float sm = e0 + e1;
      #pragma unroll
      for (int o = 32; o >= 1; o >>= 1) sm += __shfl_xor(sm, o);
      const float inv = 1.f / sm;
      al0[qi] = e0 * inv; al1[qi] = e1 * inv;
    }
    float4 accA[4], accB[4];
    #pragma unroll
    for (int qi = 0; qi < 4; ++qi) {
      accA[qi] = make_float4(0.f,0.f,0.f,0.f);
      accB[qi] = make_float4(0.f,0.f,0.f,0.f);
    }
    for (int s = 0; s < TT; ++s) {
      const float4 mv = *(const float4*)&Msh[s][lane << 2];
      float4 mv2 = make_float4(0.f,0.f,0.f,0.f);
      if (lane < 2) mv2 = *(const float4*)&Msh[s][(64 + lane) << 2];
      #pragma unroll
      for (int qi = 0; qi < 4; ++qi) {
        const float av = __shfl((s < 64) ? al0[qi] : al1[qi], s & 63);
        FMA4(accA[qi], av, mv);
        FMA4(accB[qi], av, mv2);
      }
    }
    #pragma unroll
    for (int qi = 0; qi < 4; ++qi) {
      const int t = t0 + qi;
      if (t < TT) {
        float* dst = &att[((size_t)b * TT + t) * 264];
        *(float4*)&dst[lane << 2] = accA[qi];
        if (lane < 2) *(float4*)&dst[256 + (lane << 2)] = accB[qi];
      }
    }
  }
}

// ---------------------------------------------------------------------------
// K7b: logits + log_softmax. 8 lanes per node (7 classes), 32 nodes/block.
// ---------------------------------------------------------------------------
__global__ __launch_bounds__(256) void logits_k(
    const float* __restrict__ hid, const float* __restrict__ Ws,
    const float* __restrict__ bs, float* __restrict__ out)
{
  const int tid = threadIdx.x;
  const int n = blockIdx.x * 32 + (tid >> 3);
  const int c = tid & 7;
  float lg = -3.0e38f;
  if (c < 7) {
    lg = bs[c];
    const float* hrow = &hid[(size_t)n * 64];
    #pragma unroll
    for (int k = 0; k < 64; ++k) lg += hrow[k] * Ws[k*7 + c];
  }
  float mx = lg;
  #pragma unroll
  for (int o = 4; o >= 1; o >>= 1) mx = fmaxf(mx, __shfl_xor(mx, o, 8));
  float e = (c < 7) ? __expf(lg - mx) : 0.f;
  float sm = e;
  #pragma unroll
  for (int o = 4; o >= 1; o >>= 1) sm += __shfl_xor(sm, o, 8);
  if (c < 7) out[(size_t)n * 7 + c] = lg - mx - __logf(sm);
}

// ---------------------------------------------------------------------------
extern "C" void kernel_launch(void* const* d_in, const int* in_sizes, int n_in,
                              void* d_out, int out_size, void* d_ws, size_t ws_size,
                              hipStream_t stream)
{
  const float* textf  = (const float*)d_in[0];
  const float* acouf  = (const float*)d_in[1];
  const float* visuf  = (const float*)d_in[2];
  const int*   spk    = (const int*)  d_in[3];
  const float* Wf     = (const float*)d_in[4];
  const float* bfv    = (const float*)d_in[5];
  const float* basis  = (const float*)d_in[6];
  const float* comp   = (const float*)d_in[7];
  const float* root   = (const float*)d_in[8];
  const float* brg    = (const float*)d_in[9];
  const float* Wrel   = (const float*)d_in[10];
  const float* brel   = (const float*)d_in[11];
  const float* Wroot2 = (const float*)d_in[12];
  const float* Wma    = (const float*)d_in[13];
  const float* bma    = (const float*)d_in[14];
  const float* Wl     = (const float*)d_in[15];
  const float* bl     = (const float*)d_in[16];
  const float* Wsm    = (const float*)d_in[17];
  const float* bsm    = (const float*)d_in[18];

  float* ws    = (float*)d_ws;
  float* wrels = ws;                         // 115200
  float* xb    = ws + 115200;                // N*200 = 5632000
  float* xr    = xb + 5632000;               // N*576 = 16220160
  float* h1    = xr + 16220160;              // N*64  = 1802240
  float* h2    = h1 + 1802240;               // N*64  = 1802240
  float* agg   = xr;                         // alias (xr dead after rgcn_agg)
  float* attb  = xr;                         // alias (agg dead after mgemm<3>)
  float* Xq    = xr + 7434240;               // alias upper half of xr region
  float* hid   = h1;                         // alias (h1 dead after mgemm<3>)
  float* outp  = (float*)d_out;

  wrels_k<<<450, 256, 0, stream>>>(basis, comp, root, wrels);
  mgemm_k<0,false><<<dim3(4,220), 256, 0, stream>>>(textf, acouf, visuf, Wf, bfv, xb, 200, 300);
  mgemm_k<1,false><<<dim3(9,220), 256, 0, stream>>>(xb, nullptr, nullptr, wrels, nullptr, xr, 576, 200);
  rgcn_agg_k<<<7040, 256, 0, stream>>>(xr, spk, brg, h1);
  gsum_k<<<7040, 256, 0, stream>>>(h1, agg);
  mgemm_k<3,false><<<dim3(1,220), 256, 0, stream>>>(agg, h1, Wroot2, Wrel, brel, h2, 64, 128);
  mgemm_k<2,false><<<dim3(5,220), 256, 0, stream>>>(xb, h2, nullptr, Wma, bma, Xq, 264, 264);
  attn_k<<<256, 512, 0, stream>>>(xb, h2, Xq, attb);
  mgemm_k<4,true><<<dim3(1,220), 256, 0, stream>>>(attb, nullptr, nullptr, Wl, bl, hid, 64, 264);
  logits_k<<<880, 256, 0, stream>>>(hid, Wsm, bsm, outp);
}

// Round 3
// 470.976 us; speedup vs baseline: 1.7139x; 1.3091x over previous
//
#include <hip/hip_runtime.h>

#define TT   110          // max_seq_len
#define BBD  256          // num dialogues
#define NND  28160        // TT*BBD
#define WIN  10

typedef __bf16 bf16x8 __attribute__((ext_vector_type(8)));
typedef __bf16 bf16x4 __attribute__((ext_vector_type(4)));
typedef float  f32x4  __attribute__((ext_vector_type(4)));

__device__ __forceinline__ int imax(int a, int b){ return a > b ? a : b; }
__device__ __forceinline__ int imin(int a, int b){ return a < b ? a : b; }

#define FMA4(ACC, S, B) { (ACC).x += (S)*(B).x; (ACC).y += (S)*(B).y; \
                          (ACC).z += (S)*(B).z; (ACC).w += (S)*(B).w; }

// ---------------------------------------------------------------------------
// K0: Wrels[r][f][h] = sum_nb comp[r][nb]*basis[nb][f][h]  (r<8); Wrels[8]=root
// ---------------------------------------------------------------------------
__global__ __launch_bounds__(256) void wrels_k(
    const float* __restrict__ basis, const float* __restrict__ comp,
    const float* __restrict__ root, float* __restrict__ wrels)
{
  int idx = blockIdx.x * 256 + threadIdx.x;        // 9*12800 = 115200
  if (idx >= 115200) return;
  int r = idx / 12800, fh = idx % 12800;
  float v;
  if (r < 8) {
    v = 0.f;
    #pragma unroll
    for (int nb = 0; nb < 30; ++nb) v += comp[r*30 + nb] * basis[nb*12800 + fh];
  } else {
    v = root[fh];
  }
  wrels[idx] = v;
}

// ---------------------------------------------------------------------------
// MFMA bf16 GEMM, A-panel-resident version.
// C[M x Ncols] = A[M x K] * B[K x Ncols] (+bias, opt ReLU)
// BM=128, 512 thr = 8 waves (4M x 2N); each wave 32x32 = 2x2 frags of
// v_mfma_f32_16x16x32_bf16. The FULL A panel (128 x K) is staged f32->bf16
// into LDS ONCE (A fetched from HBM exactly once per kernel), then we loop
// over NCB column-blocks of 64 x NK K-tiles, staging only the tiny B tile
// (L2-resident weights) per iteration.
// MODE 0: fusion   A=concat(textf,acouf,visuf) gathered (n=b*T+t), B=Wf[300x200]
// MODE 1: xr       A=x[N x 200],  B=wrels[(cb)][k][c&63]
// MODE 2: Xq       A=[x | h2],    B=Wma[264x264]
// MODE 3: h2       A=[agg | h1],  B=[Wrel ; Wroot2]
// MODE 4: hidden   A=att[N x 264],B=Wl[264x64], RELU
// ---------------------------------------------------------------------------
template<int MODE, int KDIM, int NCB, bool RELU>
__global__ __launch_bounds__(512) void mgemm_k(
    const float* __restrict__ p0, const float* __restrict__ p1,
    const float* __restrict__ p2, const float* __restrict__ p3,
    const float* __restrict__ bias, float* __restrict__ C,
    int Ncols)
{
  constexpr int NK  = (KDIM + 31) >> 5;
  constexpr int KS  = NK << 5;
  constexpr int LDA = KS + 8;          // stride pad: 16B-aligned rows, ~2-way banks
  __shared__ __align__(16) __bf16 Ash[128][LDA];
  __shared__ __align__(16) __bf16 Bsh[64][40];

  const int tid = threadIdx.x;
  const int m0 = blockIdx.x * 128;

  // ---- stage full A panel (f32 -> bf16), once ----
  {
    const int ar  = tid >> 2;          // row 0..127
    const int akb = (tid & 3) << 3;    // k-chunk of 8
    const int n = m0 + ar;
    int base1 = 0, base2 = 0;
    if constexpr (MODE == 0) { const int t = n % TT, b = n / TT; base1 = (t*BBD+b)*100; }
    else if constexpr (MODE == 1) { base1 = n*200; }
    else if constexpr (MODE == 2) { base1 = n*200; base2 = n*64; }
    else if constexpr (MODE == 3) { base1 = n*64;  base2 = n*64; }
    else                          { base1 = n*264; }
    for (int j = 0; j < NK; ++j) {
      bf16x8 v;
      #pragma unroll
      for (int e = 0; e < 8; ++e) {
        const int gk = (j << 5) + akb + e;
        float x = 0.f;
        if (gk < KDIM) {
          if constexpr (MODE == 0)
            x = (gk < 100) ? p0[base1+gk] : (gk < 200) ? p1[base1+gk-100] : p2[base1+gk-200];
          else if constexpr (MODE == 2)
            x = (gk < 200) ? p0[base1+gk] : p1[base2+gk-200];
          else if constexpr (MODE == 3)
            x = (gk < 64) ? p0[base1+gk] : p1[base2+gk-64];
          else
            x = p0[base1+gk];
        }
        v[e] = (__bf16)x;
      }
      *(bf16x8*)&Ash[ar][(j << 5) + akb] = v;
    }
  }
  __syncthreads();

  const int wid = tid >> 6, lane = tid & 63;
  const int wm = wid >> 1, wn = wid & 1;       // 4M x 2N waves
  const int fr = lane & 15;
  const int fk = (lane >> 4) << 3;
  const int bc = tid & 63;                     // B stage: col
  const int bkq = (tid >> 6) << 2;             //          k-chunk of 4
  const int row0 = (lane >> 4) << 2;

  for (int cb = 0; cb < NCB; ++cb) {
    const int n0 = cb << 6;
    const int gc = n0 + bc;
    f32x4 acc[2][2];
    #pragma unroll
    for (int f = 0; f < 2; ++f)
      #pragma unroll
      for (int g = 0; g < 2; ++g) acc[f][g] = (f32x4){0.f,0.f,0.f,0.f};

    for (int kt = 0; kt < NK; ++kt) {
      const int k0 = kt << 5;
      { // stage B tile (f32 -> bf16), transposed: Bsh[col][k]
        bf16x4 v;
        #pragma unroll
        for (int e = 0; e < 4; ++e) {
          const int gk = k0 + bkq + e;
          float x = 0.f;
          if (gk < KDIM && gc < Ncols) {
            if constexpr (MODE == 0)      x = p3[gk*200 + gc];
            else if constexpr (MODE == 1) x = p3[cb*12800 + gk*64 + bc];
            else if constexpr (MODE == 2) x = p3[gk*264 + gc];
            else if constexpr (MODE == 3) x = (gk < 64) ? p3[gk*64 + gc] : p2[(gk-64)*64 + gc];
            else                          x = p3[gk*64 + gc];
          }
          v[e] = (__bf16)x;
        }
        *(bf16x4*)&Bsh[bc][bkq] = v;
      }
      __syncthreads();
      bf16x8 af[2], bfv[2];
      #pragma unroll
      for (int f = 0; f < 2; ++f) af[f] = *(bf16x8*)&Ash[wm*32 + f*16 + fr][k0 + fk];
      #pragma unroll
      for (int g = 0; g < 2; ++g) bfv[g] = *(bf16x8*)&Bsh[wn*32 + g*16 + fr][fk];
      #pragma unroll
      for (int f = 0; f < 2; ++f)
        #pragma unroll
        for (int g = 0; g < 2; ++g)
          acc[f][g] = __builtin_amdgcn_mfma_f32_16x16x32_bf16(af[f], bfv[g], acc[f][g], 0, 0, 0);
      __syncthreads();
    }
    // epilogue for this column block: D col=lane&15, row=(lane>>4)*4+reg
    #pragma unroll
    for (int g = 0; g < 2; ++g) {
      const int col = n0 + wn*32 + g*16 + fr;
      if (col < Ncols) {
        const float bv = bias ? bias[col] : 0.f;
        #pragma unroll
        for (int f = 0; f < 2; ++f) {
          const int gm0 = m0 + wm*32 + f*16 + row0;
          #pragma unroll
          for (int r = 0; r < 4; ++r) {
            float v = acc[f][g][r] + bv;
            if (RELU) v = fmaxf(v, 0.f);
            C[(size_t)(gm0 + r) * Ncols + col] = v;
          }
        }
      }
    }
  }
}

// ---------------------------------------------------------------------------
// K3: RGCN windowed per-relation mean aggregation. One wave per dst node.
// ---------------------------------------------------------------------------
__global__ __launch_bounds__(256) void rgcn_agg_k(
    const float* __restrict__ xr, const int* __restrict__ spk,
    const float* __restrict__ brg, float* __restrict__ h1)
{
  const int n = (blockIdx.x << 2) + (threadIdx.x >> 6);
  const int lane = threadIdx.x & 63;
  const int t = n % TT, b = n / TT;
  const int si2 = spk[t * BBD + b] << 1;
  const int jlo = imax(t - WIN, 0), jhi = imin(t + WIN, TT - 1);
  float a00=0.f, a01=0.f, a10=0.f, a11=0.f;
  int c00=0, c01=0, c10=0, c11=0;
  const size_t rb = (size_t)b * TT;
  for (int j = jlo; j <= jhi; ++j) {
    const int s0 = spk[j * BBD + b];
    const int dir = (j >= t) ? 1 : 0;
    const int r = (s0 << 2) + si2 + dir;
    const float v = xr[(rb + j) * 576 + (r << 6) + lane];
    if (s0) { if (dir) { a11 += v; ++c11; } else { a10 += v; ++c10; } }
    else    { if (dir) { a01 += v; ++c01; } else { a00 += v; ++c00; } }
  }
  float res = a00 / (float)imax(c00,1) + a01 / (float)imax(c01,1)
            + a10 / (float)imax(c10,1) + a11 / (float)imax(c11,1);
  res += xr[(size_t)n * 576 + 512 + lane] + brg[lane];
  h1[(size_t)n * 64 + lane] = res;
}

// K4a: agg[n] = sum over window of h1[j]
__global__ __launch_bounds__(256) void gsum_k(
    const float* __restrict__ h1, float* __restrict__ agg)
{
  const int n = (blockIdx.x << 2) + (threadIdx.x >> 6);
  const int lane = threadIdx.x & 63;
  const int t = n % TT, b = n / TT;
  const int jlo = imax(t - WIN, 0), jhi = imin(t + WIN, TT - 1);
  float a = 0.f;
  const size_t rb = (size_t)b * TT;
  for (int j = jlo; j <= jhi; ++j) a += h1[(rb + j) * 64 + lane];
  agg[(size_t)n * 64 + lane] = a;
}

// ---------------------------------------------------------------------------
// K6: matching attention, one block (512 thr) per dialogue.
// ---------------------------------------------------------------------------
__global__ __launch_bounds__(512) void attn_k(
    const float* __restrict__ x, const float* __restrict__ h2,
    const float* __restrict__ Xq, float* __restrict__ att)
{
  __shared__ float Msh[TT][268];
  __shared__ float Qsh[8][4][268];
  const int b = blockIdx.x;
  const int tid = threadIdx.x;
  for (int idx = tid; idx < TT * 66; idx += 512) {
    const int row = idx / 66, c4 = idx % 66;
    const size_t node = (size_t)b * TT + row;
    float4 v;
    if (c4 < 50) v = *(const float4*)&x[node * 200 + (c4 << 2)];
    else         v = *(const float4*)&h2[node * 64 + ((c4 - 50) << 2)];
    *(float4*)&Msh[row][c4 << 2] = v;
  }
  __syncthreads();
  const int w = tid >> 6, lane = tid & 63;
  for (int p = 0; p < 4; ++p) {
    const int t0 = (p << 5) + (w << 2);
    if (t0 >= TT) break;                      // uniform per wave
    #pragma unroll
    for (int qi = 0; qi < 4; ++qi) {
      const int t = t0 + qi;
      if (t < TT) {
        const float* src = &Xq[((size_t)b * TT + t) * 264];
        *(float4*)&Qsh[w][qi][lane << 2] = *(const float4*)&src[lane << 2];
        if (lane < 2)
          *(float4*)&Qsh[w][qi][(64 + lane) << 2] = *(const float4*)&src[(64 + lane) << 2];
      }
    }
    float s0[4] = {0,0,0,0}, s1[4] = {0,0,0,0};
    for (int d4 = 0; d4 < 66; ++d4) {
      const float4 m0 = *(const float4*)&Msh[lane][d4 << 2];
      float4 m1 = make_float4(0.f,0.f,0.f,0.f);
      if (lane < 46) m1 = *(const float4*)&Msh[64 + lane][d4 << 2];
      #pragma unroll
      for (int qi = 0; qi < 4; ++qi) {
        const float4 q = *(const float4*)&Qsh[w][qi][d4 << 2];
        s0[qi] += q.x*m0.x + q.y*m0.y + q.z*m0.z + q.w*m0.w;
        s1[qi] += q.x*m1.x + q.y*m1.y + q.z*m1.z + q.w*m1.w;
      }
    }
    float al0[4], al1[4];
    #pragma unroll
    for (int qi = 0; qi < 4; ++qi) {
      const float v0 = tanhf(s0[qi]);
      const float v1 = (lane < 46) ? tanhf(s1[qi]) : -3.0e38f;
      float mx = fmaxf(v0, v1);
      #pragma unroll
      for (int o = 32; o >= 1; o >>= 1) mx = fmaxf(mx, __shfl_xor(mx, o));
      const float e0 = __expf(v0 - mx);
      const float e1 = (lane < 46) ? __expf(v1 - mx) : 0.f;
      float sm = e0 + e1;
      #pragma unroll
      for (int o = 32; o >= 1; o >>= 1) sm += __shfl_xor(sm, o);
      const float inv = 1.f / sm;
      al0[qi] = e0 * inv; al1[qi] = e1 * inv;
    }
    float4 accA[4], accB[4];
    #pragma unroll
    for (int qi = 0; qi < 4; ++qi) {
      accA[qi] = make_float4(0.f,0.f,0.f,0.f);
      accB[qi] = make_float4(0.f,0.f,0.f,0.f);
    }
    for (int s = 0; s < TT; ++s) {
      const float4 mv = *(const float4*)&Msh[s][lane << 2];
      float4 mv2 = make_float4(0.f,0.f,0.f,0.f);
      if (lane < 2) mv2 = *(const float4*)&Msh[s][(64 + lane) << 2];
      #pragma unroll
      for (int qi = 0; qi < 4; ++qi) {
        const float av = __shfl((s < 64) ? al0[qi] : al1[qi], s & 63);
        FMA4(accA[qi], av, mv);
        FMA4(accB[qi], av, mv2);
      }
    }
    #pragma unroll
    for (int qi = 0; qi < 4; ++qi) {
      const int t = t0 + qi;
      if (t < TT) {
        float* dst = &att[((size_t)b * TT + t) * 264];
        *(float4*)&dst[lane << 2] = accA[qi];
        if (lane < 2) *(float4*)&dst[256 + (lane << 2)] = accB[qi];
      }
    }
  }
}

// ---------------------------------------------------------------------------
// K7b: logits + log_softmax. 8 lanes per node (7 classes), 32 nodes/block.
// ---------------------------------------------------------------------------
__global__ __launch_bounds__(256) void logits_k(
    const float* __restrict__ hid, const float* __restrict__ Ws,
    const float* __restrict__ bs, float* __restrict__ out)
{
  const int tid = threadIdx.x;
  const int n = blockIdx.x * 32 + (tid >> 3);
  const int c = tid & 7;
  float lg = -3.0e38f;
  if (c < 7) {
    lg = bs[c];
    const float* hrow = &hid[(size_t)n * 64];
    #pragma unroll
    for (int k = 0; k < 64; ++k) lg += hrow[k] * Ws[k*7 + c];
  }
  float mx = lg;
  #pragma unroll
  for (int o = 4; o >= 1; o >>= 1) mx = fmaxf(mx, __shfl_xor(mx, o, 8));
  float e = (c < 7) ? __expf(lg - mx) : 0.f;
  float sm = e;
  #pragma unroll
  for (int o = 4; o >= 1; o >>= 1) sm += __shfl_xor(sm, o, 8);
  if (c < 7) out[(size_t)n * 7 + c] = lg - mx - __logf(sm);
}

// ---------------------------------------------------------------------------
extern "C" void kernel_launch(void* const* d_in, const int* in_sizes, int n_in,
                              void* d_out, int out_size, void* d_ws, size_t ws_size,
                              hipStream_t stream)
{
  const float* textf  = (const float*)d_in[0];
  const float* acouf  = (const float*)d_in[1];
  const float* visuf  = (const float*)d_in[2];
  const int*   spk    = (const int*)  d_in[3];
  const float* Wf     = (const float*)d_in[4];
  const float* bfv    = (const float*)d_in[5];
  const float* basis  = (const float*)d_in[6];
  const float* comp   = (const float*)d_in[7];
  const float* root   = (const float*)d_in[8];
  const float* brg    = (const float*)d_in[9];
  const float* Wrel   = (const float*)d_in[10];
  const float* brel   = (const float*)d_in[11];
  const float* Wroot2 = (const float*)d_in[12];
  const float* Wma    = (const float*)d_in[13];
  const float* bma    = (const float*)d_in[14];
  const float* Wl     = (const float*)d_in[15];
  const float* bl     = (const float*)d_in[16];
  const float* Wsm    = (const float*)d_in[17];
  const float* bsm    = (const float*)d_in[18];

  float* ws    = (float*)d_ws;
  float* wrels = ws;                         // 115200
  float* xb    = ws + 115200;                // N*200 = 5632000
  float* xr    = xb + 5632000;               // N*576 = 16220160
  float* h1    = xr + 16220160;              // N*64  = 1802240
  float* h2    = h1 + 1802240;               // N*64  = 1802240
  float* agg   = xr;                         // alias (xr dead after rgcn_agg)
  float* attb  = xr;                         // alias (agg dead after mgemm<3>)
  float* Xq    = xr + 7434240;               // alias upper half of xr region
  float* hid   = h1;                         // alias (h1 dead after mgemm<3>)
  float* outp  = (float*)d_out;

  wrels_k<<<450, 256, 0, stream>>>(basis, comp, root, wrels);
  mgemm_k<0,300,4,false><<<220, 512, 0, stream>>>(textf, acouf, visuf, Wf, bfv, xb, 200);
  mgemm_k<1,200,9,false><<<220, 512, 0, stream>>>(xb, nullptr, nullptr, wrels, nullptr, xr, 576);
  rgcn_agg_k<<<7040, 256, 0, stream>>>(xr, spk, brg, h1);
  gsum_k<<<7040, 256, 0, stream>>>(h1, agg);
  mgemm_k<3,128,1,false><<<220, 512, 0, stream>>>(agg, h1, Wroot2, Wrel, brel, h2, 64);
  mgemm_k<2,264,5,false><<<220, 512, 0, stream>>>(xb, h2, nullptr, Wma, bma, Xq, 264);
  attn_k<<<256, 512, 0, stream>>>(xb, h2, Xq, attb);
  mgemm_k<4,264,1,true><<<220, 512, 0, stream>>>(attb, nullptr, nullptr, Wl, bl, hid, 64);
  logits_k<<<880, 256, 0, stream>>>(hid, Wsm, bsm, outp);
}

// Round 4
// 382.049 us; speedup vs baseline: 2.1128x; 1.2328x over previous
//
#include <hip/hip_runtime.h>

#define TT   110          // max_seq_len
#define BBD  256          // num dialogues
#define NND  28160        // TT*BBD
#define WIN  10

typedef __bf16 bf16x8 __attribute__((ext_vector_type(8)));
typedef __bf16 bf16x4 __attribute__((ext_vector_type(4)));
typedef float  f32x4  __attribute__((ext_vector_type(4)));

__device__ __forceinline__ int imax(int a, int b){ return a > b ? a : b; }
__device__ __forceinline__ int imin(int a, int b){ return a < b ? a : b; }

// ---------------------------------------------------------------------------
// K0: Wrels[r][f][h] = sum_nb comp[r][nb]*basis[nb][f][h]  (r<8); Wrels[8]=root
// ---------------------------------------------------------------------------
__global__ __launch_bounds__(256) void wrels_k(
    const float* __restrict__ basis, const float* __restrict__ comp,
    const float* __restrict__ root, float* __restrict__ wrels)
{
  int idx = blockIdx.x * 256 + threadIdx.x;        // 9*12800 = 115200
  if (idx >= 115200) return;
  int r = idx / 12800, fh = idx % 12800;
  float v;
  if (r < 8) {
    v = 0.f;
    #pragma unroll
    for (int nb = 0; nb < 30; ++nb) v += comp[r*30 + nb] * basis[nb*12800 + fh];
  } else {
    v = root[fh];
  }
  wrels[idx] = v;
}

// ---------------------------------------------------------------------------
// MFMA bf16 GEMM, A-panel-resident. C = A*B (+bias, opt ReLU).
// BM=128, 512 thr = 8 waves (4M x 2N), wave tile 32x32 (2x2 frags 16x16x32).
// Full 128-row A panel staged to LDS once; loop NCB column blocks.
// OSTRIDE==0: C f32 row-stride Ncols. OSTRIDE>0: C bf16 hi plane (row-stride
// OSTRIDE) + lo plane at +OSTRIDE*NND (hi/lo split for downstream precision).
// ---------------------------------------------------------------------------
template<int MODE, int KDIM, int NCB, bool RELU, int OSTRIDE = 0>
__global__ __launch_bounds__(512) void mgemm_k(
    const float* __restrict__ p0, const float* __restrict__ p1,
    const float* __restrict__ p2, const float* __restrict__ p3,
    const float* __restrict__ bias, float* __restrict__ C,
    int Ncols)
{
  constexpr int NK  = (KDIM + 31) >> 5;
  constexpr int KS  = NK << 5;
  constexpr int LDA = KS + 8;
  __shared__ __align__(16) __bf16 Ash[128][LDA];
  __shared__ __align__(16) __bf16 Bsh[64][40];

  const int tid = threadIdx.x;
  const int m0 = blockIdx.x * 128;

  // ---- stage full A panel (f32 -> bf16), once ----
  {
    const int ar  = tid >> 2;          // row 0..127
    const int akb = (tid & 3) << 3;    // k-chunk of 8
    const int n = m0 + ar;
    int base1 = 0, base2 = 0;
    if constexpr (MODE == 0) { const int t = n % TT, b = n / TT; base1 = (t*BBD+b)*100; }
    else if constexpr (MODE == 1) { base1 = n*200; }
    else if constexpr (MODE == 2) { base1 = n*200; base2 = n*64; }
    else if constexpr (MODE == 3) { base1 = n*64;  base2 = n*64; }
    else                          { base1 = n*264; }
    for (int j = 0; j < NK; ++j) {
      bf16x8 v;
      #pragma unroll
      for (int e = 0; e < 8; ++e) {
        const int gk = (j << 5) + akb + e;
        float x = 0.f;
        if (gk < KDIM) {
          if constexpr (MODE == 0)
            x = (gk < 100) ? p0[base1+gk] : (gk < 200) ? p1[base1+gk-100] : p2[base1+gk-200];
          else if constexpr (MODE == 2)
            x = (gk < 200) ? p0[base1+gk] : p1[base2+gk-200];
          else if constexpr (MODE == 3)
            x = (gk < 64) ? p0[base1+gk] : p1[base2+gk-64];
          else
            x = p0[base1+gk];
        }
        v[e] = (__bf16)x;
      }
      *(bf16x8*)&Ash[ar][(j << 5) + akb] = v;
    }
  }
  __syncthreads();

  const int wid = tid >> 6, lane = tid & 63;
  const int wm = wid >> 1, wn = wid & 1;       // 4M x 2N waves
  const int fr = lane & 15;
  const int fk = (lane >> 4) << 3;
  const int bc = tid & 63;                     // B stage: col
  const int bkq = (tid >> 6) << 2;             //          k-chunk of 4
  const int row0 = (lane >> 4) << 2;

  for (int cb = 0; cb < NCB; ++cb) {
    const int n0 = cb << 6;
    const int gc = n0 + bc;
    f32x4 acc[2][2];
    #pragma unroll
    for (int f = 0; f < 2; ++f)
      #pragma unroll
      for (int g = 0; g < 2; ++g) acc[f][g] = (f32x4){0.f,0.f,0.f,0.f};

    for (int kt = 0; kt < NK; ++kt) {
      const int k0 = kt << 5;
      { // stage B tile (f32 -> bf16), transposed: Bsh[col][k]
        bf16x4 v;
        #pragma unroll
        for (int e = 0; e < 4; ++e) {
          const int gk = k0 + bkq + e;
          float x = 0.f;
          if (gk < KDIM && gc < Ncols) {
            if constexpr (MODE == 0)      x = p3[gk*200 + gc];
            else if constexpr (MODE == 1) x = p3[cb*12800 + gk*64 + bc];
            else if constexpr (MODE == 2) x = p3[gk*264 + gc];
            else if constexpr (MODE == 3) x = (gk < 64) ? p3[gk*64 + gc] : p2[(gk-64)*64 + gc];
            else                          x = p3[gk*64 + gc];
          }
          v[e] = (__bf16)x;
        }
        *(bf16x4*)&Bsh[bc][bkq] = v;
      }
      __syncthreads();
      bf16x8 af[2], bfv[2];
      #pragma unroll
      for (int f = 0; f < 2; ++f) af[f] = *(bf16x8*)&Ash[wm*32 + f*16 + fr][k0 + fk];
      #pragma unroll
      for (int g = 0; g < 2; ++g) bfv[g] = *(bf16x8*)&Bsh[wn*32 + g*16 + fr][fk];
      #pragma unroll
      for (int f = 0; f < 2; ++f)
        #pragma unroll
        for (int g = 0; g < 2; ++g)
          acc[f][g] = __builtin_amdgcn_mfma_f32_16x16x32_bf16(af[f], bfv[g], acc[f][g], 0, 0, 0);
      __syncthreads();
    }
    // epilogue: D col=lane&15, row=(lane>>4)*4+reg
    #pragma unroll
    for (int g = 0; g < 2; ++g) {
      const int col = n0 + wn*32 + g*16 + fr;
      if (col < Ncols) {
        const float bv = bias ? bias[col] : 0.f;
        #pragma unroll
        for (int f = 0; f < 2; ++f) {
          const int gm0 = m0 + wm*32 + f*16 + row0;
          #pragma unroll
          for (int r = 0; r < 4; ++r) {
            float v = acc[f][g][r] + bv;
            if (RELU) v = fmaxf(v, 0.f);
            if constexpr (OSTRIDE > 0) {
              __bf16* Cb = (__bf16*)C;
              const size_t o = (size_t)(gm0 + r) * OSTRIDE + col;
              const __bf16 hi = (__bf16)v;
              Cb[o] = hi;
              Cb[(size_t)OSTRIDE * NND + o] = (__bf16)(v - (float)hi);
            } else {
              C[(size_t)(gm0 + r) * Ncols + col] = v;
            }
          }
        }
      }
    }
  }
}

// ---------------------------------------------------------------------------
// K3: RGCN windowed per-relation mean aggregation. One wave per dst node.
// ---------------------------------------------------------------------------
__global__ __launch_bounds__(256) void rgcn_agg_k(
    const float* __restrict__ xr, const int* __restrict__ spk,
    const float* __restrict__ brg, float* __restrict__ h1)
{
  const int n = (blockIdx.x << 2) + (threadIdx.x >> 6);
  const int lane = threadIdx.x & 63;
  const int t = n % TT, b = n / TT;
  const int si2 = spk[t * BBD + b] << 1;
  const int jlo = imax(t - WIN, 0), jhi = imin(t + WIN, TT - 1);
  float a00=0.f, a01=0.f, a10=0.f, a11=0.f;
  int c00=0, c01=0, c10=0, c11=0;
  const size_t rb = (size_t)b * TT;
  for (int j = jlo; j <= jhi; ++j) {
    const int s0 = spk[j * BBD + b];
    const int dir = (j >= t) ? 1 : 0;
    const int r = (s0 << 2) + si2 + dir;
    const float v = xr[(rb + j) * 576 + (r << 6) + lane];
    if (s0) { if (dir) { a11 += v; ++c11; } else { a10 += v; ++c10; } }
    else    { if (dir) { a01 += v; ++c01; } else { a00 += v; ++c00; } }
  }
  float res = a00 / (float)imax(c00,1) + a01 / (float)imax(c01,1)
            + a10 / (float)imax(c10,1) + a11 / (float)imax(c11,1);
  res += xr[(size_t)n * 576 + 512 + lane] + brg[lane];
  h1[(size_t)n * 64 + lane] = res;
}

// K4a: agg[n] = sum over window of h1[j]
__global__ __launch_bounds__(256) void gsum_k(
    const float* __restrict__ h1, float* __restrict__ agg)
{
  const int n = (blockIdx.x << 2) + (threadIdx.x >> 6);
  const int lane = threadIdx.x & 63;
  const int t = n % TT, b = n / TT;
  const int jlo = imax(t - WIN, 0), jhi = imin(t + WIN, TT - 1);
  float a = 0.f;
  const size_t rb = (size_t)b * TT;
  for (int j = jlo; j <= jhi; ++j) a += h1[(rb + j) * 64 + lane];
  agg[(size_t)n * 64 + lane] = a;
}

// ---------------------------------------------------------------------------
// K6: MFMA matching attention. One block (448 thr = 7 waves) per dialogue;
// wave w owns t-tile w (16 query rows). S = Xq_hi*M^T + Xq_lo*M^T (bf16
// hi/lo split on Xq), tanh+softmax in f32 (width-16 shfl reduce), alpha ->
// LDS (bf16) -> PV att = alpha * M via MTsh (M transposed in LDS).
// ---------------------------------------------------------------------------
__global__ __launch_bounds__(448) void attn_mfma_k(
    const float* __restrict__ x, const float* __restrict__ h2,
    const __bf16* __restrict__ Xq, float* __restrict__ att)
{
  __shared__ __align__(16) __bf16 Msh [TT ][272];  // 59840 B: M row-major
  __shared__ __align__(16) __bf16 MTsh[264][136];  // 71808 B: M^T (cols 110..135 zero)
  __shared__ __align__(16) __bf16 Ash [112][136];  // 30464 B: alpha (cols 112..135 zero)
  const int b = blockIdx.x;
  const int tid = threadIdx.x;
  const size_t nb = (size_t)b * TT;

  // ---- stage M (row-major) and M^T ----
  for (int idx = tid; idx < TT * 66; idx += 448) {
    const int s = idx / 66, c4 = idx % 66;
    const size_t node = nb + s;
    float4 v;
    if (c4 < 50) v = *(const float4*)&x[node * 200 + (c4 << 2)];
    else         v = *(const float4*)&h2[node * 64 + ((c4 - 50) << 2)];
    const __bf16 b0 = (__bf16)v.x, b1 = (__bf16)v.y, b2 = (__bf16)v.z, b3 = (__bf16)v.w;
    bf16x4 pk = {b0, b1, b2, b3};
    *(bf16x4*)&Msh[s][c4 << 2] = pk;
    const int d = c4 << 2;
    MTsh[d+0][s] = b0; MTsh[d+1][s] = b1; MTsh[d+2][s] = b2; MTsh[d+3][s] = b3;
  }
  for (int idx = tid; idx < 264 * 26; idx += 448) MTsh[idx / 26][110 + idx % 26] = (__bf16)0.f;
  for (int idx = tid; idx < 112 * 24; idx += 448) Ash[idx / 24][112 + idx % 24] = (__bf16)0.f;
  __syncthreads();

  const int wid = tid >> 6, lane = tid & 63;
  const int t0 = wid << 4;            // this wave's 16 query rows
  const int fr = lane & 15;
  const int g  = lane >> 4;
  const int fk = g << 3;

  // ---- S = Xq * M^T  (A rows from global bf16 hi/lo planes, B = M rows) ----
  f32x4 sacc[7];
  #pragma unroll
  for (int st = 0; st < 7; ++st) sacc[st] = (f32x4){0.f,0.f,0.f,0.f};
  const int trow = t0 + fr;
  const size_t arow = (nb + (trow < TT ? trow : TT - 1)) * 288;
  const __bf16* XqLo = Xq + (size_t)288 * NND;
  for (int kst = 0; kst < 9; ++kst) {
    const int k0 = kst << 5;
    bf16x8 aqh = *(const bf16x8*)&Xq  [arow + k0 + fk];
    bf16x8 aql = *(const bf16x8*)&XqLo[arow + k0 + fk];
    if (kst == 8 && fk != 0) {                      // k >= 264 pad: force zero
      aqh = (bf16x8){0,0,0,0,0,0,0,0};
      aql = (bf16x8){0,0,0,0,0,0,0,0};
    }
    #pragma unroll
    for (int st = 0; st < 7; ++st) {
      bf16x8 bq;
      if (kst < 8) bq = *(const bf16x8*)&Msh[st*16 + fr][k0 + fk];
      else bq = (fk == 0) ? *(const bf16x8*)&Msh[st*16 + fr][256]
                          : (bf16x8){0,0,0,0,0,0,0,0};
      sacc[st] = __builtin_amdgcn_mfma_f32_16x16x32_bf16(aqh, bq, sacc[st], 0, 0, 0);
      sacc[st] = __builtin_amdgcn_mfma_f32_16x16x32_bf16(aql, bq, sacc[st], 0, 0, 0);
    }
  }

  // ---- tanh + softmax (f32) + alpha -> LDS bf16 ----
  #pragma unroll
  for (int r = 0; r < 4; ++r) {
    float tv[7];
    #pragma unroll
    for (int st = 0; st < 7; ++st) {
      const float e2 = __expf(2.f * sacc[st][r]);
      tv[st] = 1.f - 2.f / (e2 + 1.f);              // tanh
    }
    if (fr >= 14) tv[6] = -3.0e38f;                 // s = 96+fr >= 110 invalid
    float mx = fmaxf(fmaxf(fmaxf(tv[0],tv[1]), fmaxf(tv[2],tv[3])),
                     fmaxf(fmaxf(tv[4],tv[5]), tv[6]));
    #pragma unroll
    for (int o = 8; o >= 1; o >>= 1) mx = fmaxf(mx, __shfl_xor(mx, o, 16));
    float e[7], sum = 0.f;
    #pragma unroll
    for (int st = 0; st < 7; ++st) { e[st] = __expf(tv[st] - mx); sum += e[st]; }
    #pragma unroll
    for (int o = 8; o >= 1; o >>= 1) sum += __shfl_xor(sum, o, 16);
    const float inv = 1.f / sum;
    const int tr = t0 + (g << 2) + r;
    #pragma unroll
    for (int st = 0; st < 7; ++st) Ash[tr][st*16 + fr] = (__bf16)(e[st] * inv);
  }
  __syncthreads();

  // ---- PV: att = alpha * M  (A = alpha rows, B = M^T rows) ----
  const int tr2 = t0 + (g << 2);
  for (int dt = 0; dt < 17; ++dt) {
    const int d0 = dt << 4;
    f32x4 pacc = (f32x4){0.f,0.f,0.f,0.f};
    #pragma unroll
    for (int kst = 0; kst < 4; ++kst) {
      const int k0 = kst << 5;
      const bf16x8 pa = *(const bf16x8*)&Ash [t0 + fr][k0 + fk];
      const bf16x8 pb = *(const bf16x8*)&MTsh[d0 + fr][k0 + fk];
      pacc = __builtin_amdgcn_mfma_f32_16x16x32_bf16(pa, pb, pacc, 0, 0, 0);
    }
    const int col = d0 + fr;
    if (col < 264) {
      #pragma unroll
      for (int r = 0; r < 4; ++r) {
        const int t = tr2 + r;
        if (t < TT) att[(nb + t) * 264 + col] = pacc[r];
      }
    }
  }
}

// ---------------------------------------------------------------------------
// K7b: logits + log_softmax. 8 lanes per node (7 classes), 32 nodes/block.
// ---------------------------------------------------------------------------
__global__ __launch_bounds__(256) void logits_k(
    const float* __restrict__ hid, const float* __restrict__ Ws,
    const float* __restrict__ bs, float* __restrict__ out)
{
  const int tid = threadIdx.x;
  const int n = blockIdx.x * 32 + (tid >> 3);
  const int c = tid & 7;
  float lg = -3.0e38f;
  if (c < 7) {
    lg = bs[c];
    const float* hrow = &hid[(size_t)n * 64];
    #pragma unroll
    for (int k = 0; k < 64; ++k) lg += hrow[k] * Ws[k*7 + c];
  }
  float mx = lg;
  #pragma unroll
  for (int o = 4; o >= 1; o >>= 1) mx = fmaxf(mx, __shfl_xor(mx, o, 8));
  float e = (c < 7) ? __expf(lg - mx) : 0.f;
  float sm = e;
  #pragma unroll
  for (int o = 4; o >= 1; o >>= 1) sm += __shfl_xor(sm, o, 8);
  if (c < 7) out[(size_t)n * 7 + c] = lg - mx - __logf(sm);
}

// ---------------------------------------------------------------------------
extern "C" void kernel_launch(void* const* d_in, const int* in_sizes, int n_in,
                              void* d_out, int out_size, void* d_ws, size_t ws_size,
                              hipStream_t stream)
{
  const float* textf  = (const float*)d_in[0];
  const float* acouf  = (const float*)d_in[1];
  const float* visuf  = (const float*)d_in[2];
  const int*   spk    = (const int*)  d_in[3];
  const float* Wf     = (const float*)d_in[4];
  const float* bfv    = (const float*)d_in[5];
  const float* basis  = (const float*)d_in[6];
  const float* comp   = (const float*)d_in[7];
  const float* root   = (const float*)d_in[8];
  const float* brg    = (const float*)d_in[9];
  const float* Wrel   = (const float*)d_in[10];
  const float* brel   = (const float*)d_in[11];
  const float* Wroot2 = (const float*)d_in[12];
  const float* Wma    = (const float*)d_in[13];
  const float* bma    = (const float*)d_in[14];
  const float* Wl     = (const float*)d_in[15];
  const float* bl     = (const float*)d_in[16];
  const float* Wsm    = (const float*)d_in[17];
  const float* bsm    = (const float*)d_in[18];

  float* ws    = (float*)d_ws;
  float* wrels = ws;                         // 115200
  float* xb    = ws + 115200;                // N*200 = 5632000
  float* xr    = xb + 5632000;               // N*576 = 16220160
  float* h1    = xr + 16220160;              // N*64  = 1802240
  float* h2    = h1 + 1802240;               // N*64  = 1802240
  float* agg   = xr;                         // alias (xr dead after rgcn_agg)
  float* attb  = xr;                         // alias (agg dead after mgemm<3>)
  __bf16* Xqb  = (__bf16*)(xr + 7434240);    // bf16 hi+lo planes [288*N each]
  float* hid   = h1;                         // alias (h1 dead after mgemm<3>)
  float* outp  = (float*)d_out;

  wrels_k<<<450, 256, 0, stream>>>(basis, comp, root, wrels);
  mgemm_k<0,300,4,false><<<220, 512, 0, stream>>>(textf, acouf, visuf, Wf, bfv, xb, 200);
  mgemm_k<1,200,9,false><<<220, 512, 0, stream>>>(xb, nullptr, nullptr, wrels, nullptr, xr, 576);
  rgcn_agg_k<<<7040, 256, 0, stream>>>(xr, spk, brg, h1);
  gsum_k<<<7040, 256, 0, stream>>>(h1, agg);
  mgemm_k<3,128,1,false><<<220, 512, 0, stream>>>(agg, h1, Wroot2, Wrel, brel, h2, 64);
  mgemm_k<2,264,5,false,288><<<220, 512, 0, stream>>>(xb, h2, nullptr, Wma, bma, (float*)Xqb, 264);
  attn_mfma_k<<<256, 448, 0, stream>>>(xb, h2, Xqb, attb);
  mgemm_k<4,264,1,true><<<220, 512, 0, stream>>>(attb, nullptr, nullptr, Wl, bl, hid, 64);
  logits_k<<<880, 256, 0, stream>>>(hid, Wsm, bsm, outp);
}

// Round 5
// 293.473 us; speedup vs baseline: 2.7505x; 1.3018x over previous
//
#include <hip/hip_runtime.h>

#define TT   110          // max_seq_len
#define BBD  256          // num dialogues
#define NND  28160        // TT*BBD
#define WIN  10

typedef __bf16 bf16x8 __attribute__((ext_vector_type(8)));
typedef __bf16 bf16x4 __attribute__((ext_vector_type(4)));
typedef float  f32x4  __attribute__((ext_vector_type(4)));

__device__ __forceinline__ int imax(int a, int b){ return a > b ? a : b; }
__device__ __forceinline__ int imin(int a, int b){ return a < b ? a : b; }

// ---------------------------------------------------------------------------
// K0: Wrels[r][f][h] = sum_nb comp[r][nb]*basis[nb][f][h]  (r<8); Wrels[8]=root
// ---------------------------------------------------------------------------
__global__ __launch_bounds__(256) void wrels_k(
    const float* __restrict__ basis, const float* __restrict__ comp,
    const float* __restrict__ root, float* __restrict__ wrels)
{
  int idx = blockIdx.x * 256 + threadIdx.x;        // 9*12800 = 115200
  if (idx >= 115200) return;
  int r = idx / 12800, fh = idx % 12800;
  float v;
  if (r < 8) {
    v = 0.f;
    #pragma unroll
    for (int nb = 0; nb < 30; ++nb) v += comp[r*30 + nb] * basis[nb*12800 + fh];
  } else {
    v = root[fh];
  }
  wrels[idx] = v;
}

// ---------------------------------------------------------------------------
// bgemm: B-resident MFMA GEMM. C[M x Ncols] = A * B (+bias, opt ReLU).
// Block = 128 rows x 64 cols, 512 thr = 8 waves (4M x 2N), wave tile 32x32.
// B (K x 64) staged to LDS ONCE (XOR-swizzled 16B chunks) -> ONE barrier;
// A fragments read directly from global (L2-resident) per K-tile.
// Grid = 220*NCB with bijective XCD-chunked swizzle, m-major (blocks sharing
// an A panel land on the same XCD's L2).
// MODE 0: A=concat(textf,acouf,visuf) f32 gathered (n=b*T+t), B=Wf
// MODE 1: A=xb bf16 [N x 200],  B=wrels (col-blocked)
// MODE 2: A=[xb|h2] bf16,       B=Wma
// MODE 3: A=[agg|h1] f32,       B=[Wrel ; Wroot2]
// MODE 4: A=att bf16 [N x 264], B=Wl
// OUT 0: f32 (stride Ncols). OUT 1: bf16 (stride Ncols).
// OUT 2: bf16 hi+lo planes, stride 288 (Xq for attention).
// ---------------------------------------------------------------------------
template<int MODE, int KDIM, int NCB, bool RELU, int OUT>
__global__ __launch_bounds__(512) void bgemm_k(
    const void* __restrict__ a0, const void* __restrict__ a1,
    const void* __restrict__ a2, const float* __restrict__ Bp,
    const float* __restrict__ B2p, const float* __restrict__ bias,
    void* __restrict__ Cv, int Ncols)
{
  constexpr int NK  = (KDIM + 31) >> 5;
  constexpr int KS  = NK << 5;
  constexpr int KSP = (((KS >> 3) + 7) & ~7) << 3;   // chunks multiple of 8
  __shared__ __align__(16) __bf16 Bsh[64][KSP];

  const int tid = threadIdx.x;
  // ---- bijective XCD-chunked block swizzle (m-major work order) ----
  constexpr int NWT = 220 * NCB;
  const int bid = blockIdx.x;
  const int q = NWT >> 3, r = NWT & 7;
  const int xcd = bid & 7, idx = bid >> 3;
  const int w = (xcd < r) ? xcd * (q + 1) + idx
                          : r * (q + 1) + (xcd - r) * q + idx;
  const int m0 = (w / NCB) << 7;
  const int cb = w % NCB;
  const int n0 = cb << 6;

  // ---- stage B (f32 -> bf16), swizzled, once ----
  {
    const int col = tid & 63;
    const int gc = n0 + col;
    const int kq0 = (tid >> 6) << 2;
    for (int k4 = kq0; k4 < KSP; k4 += 32) {
      bf16x4 v;
      #pragma unroll
      for (int e = 0; e < 4; ++e) {
        const int gk = k4 + e;
        float x = 0.f;
        if (gk < KDIM && gc < Ncols) {
          if constexpr (MODE == 0)      x = Bp[gk*200 + gc];
          else if constexpr (MODE == 1) x = Bp[cb*12800 + gk*64 + col];
          else if constexpr (MODE == 2) x = Bp[gk*264 + gc];
          else if constexpr (MODE == 3) x = (gk < 64) ? Bp[gk*64 + gc] : B2p[(gk-64)*64 + gc];
          else                          x = Bp[gk*64 + gc];
        }
        v[e] = (__bf16)x;
      }
      const int sw = ((((k4 >> 3) ^ (col & 7)) << 3) | (k4 & 7));
      *(bf16x4*)&Bsh[col][sw] = v;
    }
  }
  __syncthreads();

  const int wid = tid >> 6, lane = tid & 63;
  const int wm = wid >> 1, wn = wid & 1;
  const int fr = lane & 15;
  const int fk = (lane >> 4) << 3;
  const int row0 = (lane >> 4) << 2;

  f32x4 acc[2][2];
  #pragma unroll
  for (int f = 0; f < 2; ++f)
    #pragma unroll
    for (int g = 0; g < 2; ++g) acc[f][g] = (f32x4){0.f,0.f,0.f,0.f};

  #pragma unroll
  for (int kt = 0; kt < NK; ++kt) {
    const int ko = (kt << 5) + fk;
    bf16x8 af[2];
    #pragma unroll
    for (int f = 0; f < 2; ++f) {
      const int ra = m0 + wm*32 + f*16 + fr;
      if constexpr (MODE == 0) {
        const int t = ra % TT, bb = ra / TT;
        const int ab = (t*BBD + bb)*100;
        #pragma unroll
        for (int e = 0; e < 8; ++e) {
          const int gk = ko + e;
          float x = (gk < 100) ? ((const float*)a0)[ab+gk]
                  : (gk < 200) ? ((const float*)a1)[ab+gk-100]
                  : (gk < 300) ? ((const float*)a2)[ab+gk-200] : 0.f;
          af[f][e] = (__bf16)x;
        }
      } else if constexpr (MODE == 1) {
        af[f] = *(const bf16x8*)((const __bf16*)a0 + (size_t)ra*200 + ko);
      } else if constexpr (MODE == 2) {
        af[f] = (ko < 200)
              ? *(const bf16x8*)((const __bf16*)a0 + (size_t)ra*200 + ko)
              : *(const bf16x8*)((const __bf16*)a1 + (size_t)ra*64 + ko - 200);
      } else if constexpr (MODE == 3) {
        const float* src = (ko < 64) ? (const float*)a0 + (size_t)ra*64 + ko
                                     : (const float*)a1 + (size_t)ra*64 + ko - 64;
        const float4 u0 = ((const float4*)src)[0];
        const float4 u1 = ((const float4*)src)[1];
        af[f] = (bf16x8){(__bf16)u0.x,(__bf16)u0.y,(__bf16)u0.z,(__bf16)u0.w,
                         (__bf16)u1.x,(__bf16)u1.y,(__bf16)u1.z,(__bf16)u1.w};
      } else {
        af[f] = *(const bf16x8*)((const __bf16*)a0 + (size_t)ra*264 + ko);
      }
    }
    bf16x8 bfv[2];
    #pragma unroll
    for (int g = 0; g < 2; ++g) {
      const int rb_ = wn*32 + g*16 + fr;
      bfv[g] = *(const bf16x8*)&Bsh[rb_][(((ko >> 3) ^ (rb_ & 7)) << 3)];
    }
    #pragma unroll
    for (int f = 0; f < 2; ++f)
      #pragma unroll
      for (int g = 0; g < 2; ++g)
        acc[f][g] = __builtin_amdgcn_mfma_f32_16x16x32_bf16(af[f], bfv[g], acc[f][g], 0, 0, 0);
  }

  // ---- epilogue: D col=lane&15, row=(lane>>4)*4+reg ----
  #pragma unroll
  for (int g = 0; g < 2; ++g) {
    const int col = n0 + wn*32 + g*16 + fr;
    if (col < Ncols) {
      const float bv = bias ? bias[col] : 0.f;
      #pragma unroll
      for (int f = 0; f < 2; ++f) {
        const int gm0 = m0 + wm*32 + f*16 + row0;
        #pragma unroll
        for (int r2 = 0; r2 < 4; ++r2) {
          float v = acc[f][g][r2] + bv;
          if (RELU) v = fmaxf(v, 0.f);
          const int gm = gm0 + r2;
          if constexpr (OUT == 0) {
            ((float*)Cv)[(size_t)gm * Ncols + col] = v;
          } else if constexpr (OUT == 1) {
            ((__bf16*)Cv)[(size_t)gm * Ncols + col] = (__bf16)v;
          } else {
            __bf16* Cb = (__bf16*)Cv;
            const size_t o = (size_t)gm * 288 + col;
            const __bf16 hi = (__bf16)v;
            Cb[o] = hi;
            Cb[(size_t)288 * NND + o] = (__bf16)(v - (float)hi);
          }
        }
      }
    }
  }
}

// ---------------------------------------------------------------------------
// K3: RGCN windowed per-relation mean aggregation. One wave per dst node.
// xr is bf16 [N x 576].
// ---------------------------------------------------------------------------
__global__ __launch_bounds__(256) void rgcn_agg_k(
    const __bf16* __restrict__ xr, const int* __restrict__ spk,
    const float* __restrict__ brg, float* __restrict__ h1)
{
  const int n = (blockIdx.x << 2) + (threadIdx.x >> 6);
  const int lane = threadIdx.x & 63;
  const int t = n % TT, b = n / TT;
  const int si2 = spk[t * BBD + b] << 1;
  const int jlo = imax(t - WIN, 0), jhi = imin(t + WIN, TT - 1);
  float a00=0.f, a01=0.f, a10=0.f, a11=0.f;
  int c00=0, c01=0, c10=0, c11=0;
  const size_t rb = (size_t)b * TT;
  for (int j = jlo; j <= jhi; ++j) {
    const int s0 = spk[j * BBD + b];
    const int dir = (j >= t) ? 1 : 0;
    const int r = (s0 << 2) + si2 + dir;
    const float v = (float)xr[(rb + j) * 576 + (r << 6) + lane];
    if (s0) { if (dir) { a11 += v; ++c11; } else { a10 += v; ++c10; } }
    else    { if (dir) { a01 += v; ++c01; } else { a00 += v; ++c00; } }
  }
  float res = a00 / (float)imax(c00,1) + a01 / (float)imax(c01,1)
            + a10 / (float)imax(c10,1) + a11 / (float)imax(c11,1);
  res += (float)xr[(size_t)n * 576 + 512 + lane] + brg[lane];
  h1[(size_t)n * 64 + lane] = res;
}

// K4a: agg[n] = sum over window of h1[j]
__global__ __launch_bounds__(256) void gsum_k(
    const float* __restrict__ h1, float* __restrict__ agg)
{
  const int n = (blockIdx.x << 2) + (threadIdx.x >> 6);
  const int lane = threadIdx.x & 63;
  const int t = n % TT, b = n / TT;
  const int jlo = imax(t - WIN, 0), jhi = imin(t + WIN, TT - 1);
  float a = 0.f;
  const size_t rb = (size_t)b * TT;
  for (int j = jlo; j <= jhi; ++j) a += h1[(rb + j) * 64 + lane];
  agg[(size_t)n * 64 + lane] = a;
}

// ---------------------------------------------------------------------------
// K6: MFMA matching attention. One block (448 thr = 7 waves) per dialogue.
// x, h2 are bf16 (direct LDS copy); att written bf16.
// ---------------------------------------------------------------------------
__global__ __launch_bounds__(448) void attn_mfma_k(
    const __bf16* __restrict__ x, const __bf16* __restrict__ h2,
    const __bf16* __restrict__ Xq, __bf16* __restrict__ att)
{
  __shared__ __align__(16) __bf16 Msh [TT ][272];  // 59840 B: M row-major
  __shared__ __align__(16) __bf16 MTsh[264][136];  // 71808 B: M^T (cols 110..135 zero)
  __shared__ __align__(16) __bf16 Ash [112][136];  // 30464 B: alpha (cols 112..135 zero)
  const int b = blockIdx.x;
  const int tid = threadIdx.x;
  const size_t nb = (size_t)b * TT;

  // ---- stage M (row-major) and M^T ----
  for (int idx = tid; idx < TT * 66; idx += 448) {
    const int s = idx / 66, c4 = idx % 66;
    const size_t node = nb + s;
    bf16x4 pk;
    if (c4 < 50) pk = *(const bf16x4*)&x [node * 200 + (c4 << 2)];
    else         pk = *(const bf16x4*)&h2[node * 64 + ((c4 - 50) << 2)];
    *(bf16x4*)&Msh[s][c4 << 2] = pk;
    const int d = c4 << 2;
    MTsh[d+0][s] = pk[0]; MTsh[d+1][s] = pk[1];
    MTsh[d+2][s] = pk[2]; MTsh[d+3][s] = pk[3];
  }
  for (int idx = tid; idx < 264 * 26; idx += 448) MTsh[idx / 26][110 + idx % 26] = (__bf16)0.f;
  for (int idx = tid; idx < 112 * 24; idx += 448) Ash[idx / 24][112 + idx % 24] = (__bf16)0.f;
  __syncthreads();

  const int wid = tid >> 6, lane = tid & 63;
  const int t0 = wid << 4;
  const int fr = lane & 15;
  const int g  = lane >> 4;
  const int fk = g << 3;

  // ---- S = Xq * M^T  (A from global bf16 hi/lo planes, B = M rows) ----
  f32x4 sacc[7];
  #pragma unroll
  for (int st = 0; st < 7; ++st) sacc[st] = (f32x4){0.f,0.f,0.f,0.f};
  const int trow = t0 + fr;
  const size_t arow = (nb + (trow < TT ? trow : TT - 1)) * 288;
  const __bf16* XqLo = Xq + (size_t)288 * NND;
  for (int kst = 0; kst < 9; ++kst) {
    const int k0 = kst << 5;
    bf16x8 aqh = *(const bf16x8*)&Xq  [arow + k0 + fk];
    bf16x8 aql = *(const bf16x8*)&XqLo[arow + k0 + fk];
    if (kst == 8 && fk != 0) {
      aqh = (bf16x8){0,0,0,0,0,0,0,0};
      aql = (bf16x8){0,0,0,0,0,0,0,0};
    }
    #pragma unroll
    for (int st = 0; st < 7; ++st) {
      bf16x8 bq;
      if (kst < 8) bq = *(const bf16x8*)&Msh[st*16 + fr][k0 + fk];
      else bq = (fk == 0) ? *(const bf16x8*)&Msh[st*16 + fr][256]
                          : (bf16x8){0,0,0,0,0,0,0,0};
      sacc[st] = __builtin_amdgcn_mfma_f32_16x16x32_bf16(aqh, bq, sacc[st], 0, 0, 0);
      sacc[st] = __builtin_amdgcn_mfma_f32_16x16x32_bf16(aql, bq, sacc[st], 0, 0, 0);
    }
  }

  // ---- tanh + softmax (f32) + alpha -> LDS bf16 ----
  #pragma unroll
  for (int r = 0; r < 4; ++r) {
    float tv[7];
    #pragma unroll
    for (int st = 0; st < 7; ++st) {
      const float e2 = __expf(2.f * sacc[st][r]);
      tv[st] = 1.f - 2.f / (e2 + 1.f);
    }
    if (fr >= 14) tv[6] = -3.0e38f;
    float mx = fmaxf(fmaxf(fmaxf(tv[0],tv[1]), fmaxf(tv[2],tv[3])),
                     fmaxf(fmaxf(tv[4],tv[5]), tv[6]));
    #pragma unroll
    for (int o = 8; o >= 1; o >>= 1) mx = fmaxf(mx, __shfl_xor(mx, o, 16));
    float e[7], sum = 0.f;
    #pragma unroll
    for (int st = 0; st < 7; ++st) { e[st] = __expf(tv[st] - mx); sum += e[st]; }
    #pragma unroll
    for (int o = 8; o >= 1; o >>= 1) sum += __shfl_xor(sum, o, 16);
    const float inv = 1.f / sum;
    const int tr = t0 + (g << 2) + r;
    #pragma unroll
    for (int st = 0; st < 7; ++st) Ash[tr][st*16 + fr] = (__bf16)(e[st] * inv);
  }
  __syncthreads();

  // ---- PV: att = alpha * M  (A = alpha rows, B = M^T rows) ----
  const int tr2 = t0 + (g << 2);
  for (int dt = 0; dt < 17; ++dt) {
    const int d0 = dt << 4;
    f32x4 pacc = (f32x4){0.f,0.f,0.f,0.f};
    #pragma unroll
    for (int kst = 0; kst < 4; ++kst) {
      const int k0 = kst << 5;
      const bf16x8 pa = *(const bf16x8*)&Ash [t0 + fr][k0 + fk];
      const bf16x8 pb = *(const bf16x8*)&MTsh[d0 + fr][k0 + fk];
      pacc = __builtin_amdgcn_mfma_f32_16x16x32_bf16(pa, pb, pacc, 0, 0, 0);
    }
    const int col = d0 + fr;
    if (col < 264) {
      #pragma unroll
      for (int r = 0; r < 4; ++r) {
        const int t = tr2 + r;
        if (t < TT) att[(nb + t) * 264 + col] = (__bf16)pacc[r];
      }
    }
  }
}

// ---------------------------------------------------------------------------
// K7b: logits + log_softmax. 8 lanes per node (7 classes), 32 nodes/block.
// ---------------------------------------------------------------------------
__global__ __launch_bounds__(256) void logits_k(
    const float* __restrict__ hid, const float* __restrict__ Ws,
    const float* __restrict__ bs, float* __restrict__ out)
{
  const int tid = threadIdx.x;
  const int n = blockIdx.x * 32 + (tid >> 3);
  const int c = tid & 7;
  float lg = -3.0e38f;
  if (c < 7) {
    lg = bs[c];
    const float* hrow = &hid[(size_t)n * 64];
    #pragma unroll
    for (int k = 0; k < 64; ++k) lg += hrow[k] * Ws[k*7 + c];
  }
  float mx = lg;
  #pragma unroll
  for (int o = 4; o >= 1; o >>= 1) mx = fmaxf(mx, __shfl_xor(mx, o, 8));
  float e = (c < 7) ? __expf(lg - mx) : 0.f;
  float sm = e;
  #pragma unroll
  for (int o = 4; o >= 1; o >>= 1) sm += __shfl_xor(sm, o, 8);
  if (c < 7) out[(size_t)n * 7 + c] = lg - mx - __logf(sm);
}

// ---------------------------------------------------------------------------
extern "C" void kernel_launch(void* const* d_in, const int* in_sizes, int n_in,
                              void* d_out, int out_size, void* d_ws, size_t ws_size,
                              hipStream_t stream)
{
  const float* textf  = (const float*)d_in[0];
  const float* acouf  = (const float*)d_in[1];
  const float* visuf  = (const float*)d_in[2];
  const int*   spk    = (const int*)  d_in[3];
  const float* Wf     = (const float*)d_in[4];
  const float* bfv    = (const float*)d_in[5];
  const float* basis  = (const float*)d_in[6];
  const float* comp   = (const float*)d_in[7];
  const float* root   = (const float*)d_in[8];
  const float* brg    = (const float*)d_in[9];
  const float* Wrel   = (const float*)d_in[10];
  const float* brel   = (const float*)d_in[11];
  const float* Wroot2 = (const float*)d_in[12];
  const float* Wma    = (const float*)d_in[13];
  const float* bma    = (const float*)d_in[14];
  const float* Wl     = (const float*)d_in[15];
  const float* bl     = (const float*)d_in[16];
  const float* Wsm    = (const float*)d_in[17];
  const float* bsm    = (const float*)d_in[18];

  float* ws    = (float*)d_ws;
  // f32-unit offsets
  float*  wrels = ws;                               // 115,200
  __bf16* xb    = (__bf16*)(ws + 115200);           // N*200 bf16 = 2,816,000 f32
  __bf16* xr    = (__bf16*)(ws + 2931200);          // N*576 bf16 = 8,110,080 f32
  float*  h1    = ws + 11041280;                    // N*64 f32   = 1,802,240
  __bf16* h2    = (__bf16*)(ws + 12843520);         // N*64 bf16  =   901,120 f32
  float*  agg   = ws + 13744640;                    // N*64 f32   = 1,802,240
  __bf16* Xqb   = (__bf16*)(ws + 15546880);         // 2*N*288 bf16 = 8,110,080 f32
  __bf16* attb  = (__bf16*)(ws + 2931200);          // alias xr (dead after rgcn_agg)
  float*  hid   = ws + 13744640;                    // alias agg (dead after bgemm<3>)
  float*  outp  = (float*)d_out;

  wrels_k<<<450, 256, 0, stream>>>(basis, comp, root, wrels);
  bgemm_k<0,300,4,false,1><<<880, 512, 0, stream>>>(textf, acouf, visuf, Wf, nullptr, bfv, xb, 200);
  bgemm_k<1,200,9,false,1><<<1980, 512, 0, stream>>>(xb, nullptr, nullptr, wrels, nullptr, nullptr, xr, 576);
  rgcn_agg_k<<<7040, 256, 0, stream>>>(xr, spk, brg, h1);
  gsum_k<<<7040, 256, 0, stream>>>(h1, agg);
  bgemm_k<3,128,1,false,1><<<220, 512, 0, stream>>>(agg, h1, nullptr, Wrel, Wroot2, brel, h2, 64);
  bgemm_k<2,264,5,false,2><<<1100, 512, 0, stream>>>(xb, h2, nullptr, Wma, nullptr, bma, Xqb, 264);
  attn_mfma_k<<<256, 448, 0, stream>>>(xb, h2, Xqb, attb);
  bgemm_k<4,264,1,true,0><<<220, 512, 0, stream>>>(attb, nullptr, nullptr, Wl, nullptr, bl, hid, 64);
  logits_k<<<880, 256, 0, stream>>>(hid, Wsm, bsm, outp);
}